// Round 16
// baseline (96.146 us; speedup 1.0000x reference)
//
#include <hip/hip_runtime.h>
#include <hip/hip_bf16.h>

#define IN_DIMX 135909
#define OUT_DIMX 670091
#define DDIM 128
#define BATCH 256
#define TFEAT 100
#define NBLK 768                      // 3 blocks/CU (slim body ~130 VGPR, 48KB LDS/CU)
#define NCHUNK ((OUT_DIMX + 63) / 64) // 10471 chunks of 64 classes
#define LOG2E 1.44269504088896f

typedef __bf16 bf16_t;
typedef __attribute__((ext_vector_type(4))) float f32x4;

// ---------------- K1: embedding bag sum -> L2 normalize -> +bias -> relu ----
// ONE wave per batch row: float2 gathers, zero barriers, in-register fp8 pack.
// q8 PRE-SCALED by log2e; qf stays exact f32 for the label-logit path.
__global__ void k_query(const int* __restrict__ x, const float* __restrict__ emb,
                        const float* __restrict__ bias, float* __restrict__ qf,
                        unsigned char* __restrict__ q8) {
    const int row = blockIdx.x;
    const int lane = threadIdx.x; // 64, lane covers dims {2*lane, 2*lane+1}
    __shared__ int sidx[TFEAT];
    if (lane < 50) {
        sidx[lane] = x[row * TFEAT + lane];
        sidx[lane + 50] = x[row * TFEAT + lane + 50];
    }
    float sx = 0.f, sy = 0.f;
    #pragma unroll 10
    for (int i = 0; i < TFEAT; ++i) {
        const float2 e = ((const float2*)(emb + (size_t)sidx[i] * DDIM))[lane];
        sx += e.x; sy += e.y;
    }
    float sq = sx * sx + sy * sy;
    #pragma unroll
    for (int off = 1; off < 64; off <<= 1) sq += __shfl_xor(sq, off, 64);
    const float rn = 1.0f / sqrtf(sq);
    const float2 bb = ((const float2*)bias)[lane];
    float qx = fmaxf(sx * rn + bb.x, 0.f);
    float qy = fmaxf(sy * rn + bb.y, 0.f);
    ((float2*)(qf + row * DDIM))[lane] = make_float2(qx, qy);
    const float vx = qx * LOG2E, vy = qy * LOG2E;
    const float nx = __shfl_xor(vx, 1, 64), ny = __shfl_xor(vy, 1, 64);
    if ((lane & 1) == 0) {
        int p = __builtin_amdgcn_cvt_pk_fp8_f32(vx, vy, 0, false);
        p = __builtin_amdgcn_cvt_pk_fp8_f32(nx, ny, p, true);
        ((int*)q8)[row * 32 + (lane >> 1)] = p;
    }
}

// ---------------- K2: MFMA logits + per-block partial sum-of-exp ------------
// R14 winning skeleton and ORDER (convwrite_reload -> raw lgkm barrier ->
// MFMA -> consume; fused in-place wr reload rides across the barrier; bias in
// MFMA C-init; exp2-domain consume). THIS ROUND's single composite lever:
// nt-outer interleave (acc[4] = 16 VGPR, consumed per-column) slims the wave
// to ~130 VGPR -> 3 waves/SIMD, and NBLK=768 = exactly 3 blocks/CU: three
// anti-phased chunk streams per CU hide each other's staging waits (the
// 3-stream theory R7 could not test: its bf16 fragments blew the 170-VGPR
// threshold and it ran 2-resident with a straggler tail).
__global__ __launch_bounds__(256, 2)
void k_lse(const float* __restrict__ W, const float* __restrict__ b_out,
           const unsigned char* __restrict__ q8, float* __restrict__ partials) {
    __shared__ unsigned char lds[2][64 * DDIM]; // 2 x 8 KB fp8
    const int tid = threadIdx.x;
    const int lane = tid & 63;
    const int w = tid >> 6;
    const int l15 = lane & 15;
    const int l4 = lane >> 4;

    // A fragments: this wave's 64 batch rows, fp8 (8 bytes = i64 per frag)
    long a[4][4];
    #pragma unroll
    for (int mt = 0; mt < 4; ++mt)
        #pragma unroll
        for (int ks = 0; ks < 4; ++ks)
            a[mt][ks] = *(const long*)(q8 + (w * 64 + mt * 16 + l15) * DDIM + ks * 32 + 8 * l4);

    float rs[4][4];
    #pragma unroll
    for (int mt = 0; mt < 4; ++mt)
        #pragma unroll
        for (int r = 0; r < 4; ++r) rs[mt][r] = 0.f;

    // staging geometry: thread covers f32 elems (row = j*8 + tid>>5,
    // cols [(tid&31)*4, +4)); global access per j = contiguous 1KB/wave.
    const int srow = tid >> 5;
    const int scol4 = (tid & 31);       // 4-byte fp8 group index 0..31
    const int c8 = scol4 >> 1;          // dest 8B granule within row
    const int half = (scol4 & 1) * 4;   // byte offset within granule

    f32x4 wr[8];
    float bo_n[4];

    auto issue = [&](int ch) {
        const int cb = ch * 64;
        #pragma unroll
        for (int j = 0; j < 8; ++j) {
            int r = cb + j * 8 + srow;
            r = (r < OUT_DIMX) ? r : 0; // clamp: unconditional, in-bounds
            wr[j] = *(const f32x4*)(W + (size_t)r * DDIM + scol4 * 4);
        }
        #pragma unroll
        for (int nt = 0; nt < 4; ++nt) {
            int cc = cb + nt * 16 + l15;
            cc = (cc < OUT_DIMX) ? cc : 0;
            bo_n[nt] = b_out[cc] * LOG2E; // exp2-domain
        }
    };

    // Fused: per j, pack wr[j] -> 4 fp8 bytes, ds_write_b32, then immediately
    // reload wr[j] with the next chunk's row j (loads ride across the barrier).
    auto convwrite_reload = [&](int cur, bool has_next, int nch) {
        const int cb = nch * 64;
        #pragma unroll
        for (int j = 0; j < 8; ++j) {
            const int row = j * 8 + srow;
            const int sw = (c8 ^ (row & 7)) * 8 + half;
            int p = __builtin_amdgcn_cvt_pk_fp8_f32(wr[j][0], wr[j][1], 0, false);
            p = __builtin_amdgcn_cvt_pk_fp8_f32(wr[j][2], wr[j][3], p, true);
            *(int*)(&lds[cur][row * DDIM + sw]) = p;
            if (has_next) {
                int r = cb + j * 8 + srow;
                r = (r < OUT_DIMX) ? r : 0;
                wr[j] = *(const f32x4*)(W + (size_t)r * DDIM + scol4 * 4);
            }
        }
    };

    int cur = 0;
    issue(blockIdx.x);
    for (int ch = blockIdx.x; ch < NCHUNK; ch += NBLK) {
        float bo_c[4];
        #pragma unroll
        for (int nt = 0; nt < 4; ++nt) bo_c[nt] = bo_n[nt];

        const bool has_next = (ch + NBLK < NCHUNK);
        convwrite_reload(cur, has_next, has_next ? ch + NBLK : 0);
        if (has_next) { // next chunk's b_out rides with the W loads
            const int cb = (ch + NBLK) * 64;
            #pragma unroll
            for (int nt = 0; nt < 4; ++nt) {
                int cc = cb + nt * 16 + l15;
                cc = (cc < OUT_DIMX) ? cc : 0;
                bo_n[nt] = b_out[cc] * LOG2E;
            }
        }
        // RAW barrier: wait only LDS writes; W loads stay in flight across it.
        asm volatile("s_waitcnt lgkmcnt(0)" ::: "memory");
        __builtin_amdgcn_s_barrier();
        asm volatile("" ::: "memory"); // no ds_read hoist above barrier

        const int cbase = ch * 64;
        if (cbase + 64 <= OUT_DIMX) { // full chunk: no masking
            #pragma unroll
            for (int nt = 0; nt < 4; ++nt) {
                const int row = nt * 16 + l15;
                f32x4 acc[4]; // C-init = per-class bias (exp2-domain)
                #pragma unroll
                for (int mt = 0; mt < 4; ++mt)
                    acc[mt] = (f32x4){bo_c[nt], bo_c[nt], bo_c[nt], bo_c[nt]};
                #pragma unroll
                for (int ks = 0; ks < 4; ++ks) {
                    const int g = (ks * 4 + l4) ^ (row & 7);
                    const long b = *(const long*)(&lds[cur][row * DDIM + g * 8]);
                    #pragma unroll
                    for (int mt = 0; mt < 4; ++mt)
                        acc[mt] = __builtin_amdgcn_mfma_f32_16x16x32_fp8_fp8(
                            a[mt][ks], b, acc[mt], 0, 0, 0);
                }
                #pragma unroll
                for (int mt = 0; mt < 4; ++mt)
                    #pragma unroll
                    for (int r = 0; r < 4; ++r)
                        rs[mt][r] += __builtin_amdgcn_exp2f(acc[mt][r]);
            }
        } else { // single partial tail chunk
            #pragma unroll
            for (int nt = 0; nt < 4; ++nt) {
                const int row = nt * 16 + l15;
                f32x4 acc[4];
                #pragma unroll
                for (int mt = 0; mt < 4; ++mt)
                    acc[mt] = (f32x4){bo_c[nt], bo_c[nt], bo_c[nt], bo_c[nt]};
                #pragma unroll
                for (int ks = 0; ks < 4; ++ks) {
                    const int g = (ks * 4 + l4) ^ (row & 7);
                    const long b = *(const long*)(&lds[cur][row * DDIM + g * 8]);
                    #pragma unroll
                    for (int mt = 0; mt < 4; ++mt)
                        acc[mt] = __builtin_amdgcn_mfma_f32_16x16x32_fp8_fp8(
                            a[mt][ks], b, acc[mt], 0, 0, 0);
                }
                const bool valid = (cbase + nt * 16 + l15 < OUT_DIMX);
                #pragma unroll
                for (int mt = 0; mt < 4; ++mt)
                    #pragma unroll
                    for (int r = 0; r < 4; ++r)
                        rs[mt][r] += valid ? __builtin_amdgcn_exp2f(acc[mt][r]) : 0.f;
            }
        }
        cur ^= 1;
    }

    // reduce across the 16 lanes sharing each batch row; transposed layout
    // partials[row * NBLK + blk] so k_rowlse reads coalesced.
    #pragma unroll
    for (int mt = 0; mt < 4; ++mt)
        #pragma unroll
        for (int r = 0; r < 4; ++r) {
            float v = rs[mt][r];
            v += __shfl_xor(v, 1, 64);
            v += __shfl_xor(v, 2, 64);
            v += __shfl_xor(v, 4, 64);
            v += __shfl_xor(v, 8, 64);
            if (l15 == 0) {
                const int rowb = w * 64 + mt * 16 + l4 * 4 + r;
                partials[(size_t)rowb * NBLK + blockIdx.x] = v;
            }
        }
}

// ---------------- K3: per-row logsumexp + label logit -> per-row loss -------
// partials hold sums of 2^(l*log2e) = e^l, so LSE_natural = logf(s).
__global__ void k_rowlse(const float* __restrict__ partials,
                         const int* __restrict__ y,
                         const float* __restrict__ qf,
                         const float* __restrict__ W,
                         const float* __restrict__ b_out,
                         float* __restrict__ rowloss) {
    const int i = blockIdx.x;     // batch row
    const int lane = threadIdx.x; // 64
    float s = 0.f;
    #pragma unroll
    for (int k = 0; k < NBLK / 64; ++k)
        s += partials[(size_t)i * NBLK + k * 64 + lane];
    // label logit: dot(q_i, W[y_i]) fused here (exact f32)
    const int yi = y[i];
    const float* wrow = W + (size_t)yi * DDIM;
    const float* qrow = qf + i * DDIM;
    float d = qrow[lane] * wrow[lane] + qrow[lane + 64] * wrow[lane + 64];
    #pragma unroll
    for (int off = 1; off < 64; off <<= 1) {
        s += __shfl_xor(s, off, 64);
        d += __shfl_xor(d, off, 64);
    }
    if (lane == 0) rowloss[i] = logf(s) - (d + b_out[yi]);
}

// ---------------- K4: mean over batch -> scalar loss ------------------------
__global__ void k_final(const float* __restrict__ rowloss, float* __restrict__ out) {
    const int i = threadIdx.x; // 256
    float t = rowloss[i];
    #pragma unroll
    for (int off = 1; off < 64; off <<= 1) t += __shfl_xor(t, off, 64);
    __shared__ float wred[4];
    if ((threadIdx.x & 63) == 0) wred[threadIdx.x >> 6] = t;
    __syncthreads();
    if (threadIdx.x == 0)
        out[0] = (wred[0] + wred[1] + wred[2] + wred[3]) * (1.0f / (float)BATCH);
}

extern "C" void kernel_launch(void* const* d_in, const int* in_sizes, int n_in,
                              void* d_out, int out_size, void* d_ws, size_t ws_size,
                              hipStream_t stream) {
    const int*   x     = (const int*)d_in[0];
    const int*   y     = (const int*)d_in[1];
    // d_in[2] = freeze, d_in[3] = slide (unused: exact/full softmax path)
    const float* emb   = (const float*)d_in[4];
    const float* bias  = (const float*)d_in[5];
    const float* W     = (const float*)d_in[6];
    const float* b_out = (const float*)d_in[7];
    float* out = (float*)d_out;

    char* ws = (char*)d_ws;
    unsigned char* q8 = (unsigned char*)(ws);   // 256*128 = 32 KB fp8 (q*log2e)
    float*  qf       = (float*)(ws + 65536);    // 256*128*4 = 128 KB (exact)
    float*  rowloss  = (float*)(ws + 197632);   // 1 KB
    float*  partials = (float*)(ws + 262144);   // 256*NBLK*4 = 768 KB

    k_query<<<BATCH, 64, 0, stream>>>(x, emb, bias, qf, q8);
    k_lse<<<NBLK, 256, 0, stream>>>(W, b_out, q8, partials);
    k_rowlse<<<BATCH, 64, 0, stream>>>(partials, y, qf, W, b_out, rowloss);
    k_final<<<1, 256, 0, stream>>>(rowloss, out);
}

// Round 17
// 82.046 us; speedup vs baseline: 1.1719x; 1.1719x over previous
//
#include <hip/hip_runtime.h>
#include <hip/hip_bf16.h>

#define IN_DIMX 135909
#define OUT_DIMX 670091
#define DDIM 128
#define BATCH 256
#define TFEAT 100
#define NBLK 512                      // k_lse grid: exactly 2 blocks/CU
#define NCHUNK ((OUT_DIMX + 63) / 64) // 10471 chunks of 64 classes
#define LOG2E 1.44269504088896f

typedef __bf16 bf16_t;
typedef __attribute__((ext_vector_type(4))) float f32x4;

// ---------------- K1: embedding bag sum -> L2 normalize -> +bias -> relu ----
// fp8 pack of q PRE-SCALED by log2e (k_lse consumes exp2-domain logits);
// qf stays exact f32 for the label-logit path.
__global__ void k_query(const int* __restrict__ x, const float* __restrict__ emb,
                        const float* __restrict__ bias, float* __restrict__ qf,
                        unsigned char* __restrict__ q8) {
    const int row = blockIdx.x;
    const int t = threadIdx.x; // 128 threads, one per dim
    __shared__ int sidx[TFEAT];
    __shared__ float qs[DDIM];
    if (t < TFEAT) sidx[t] = x[row * TFEAT + t];
    __syncthreads();
    float s = 0.f;
    #pragma unroll 10
    for (int i = 0; i < TFEAT; ++i) {
        s += emb[(size_t)sidx[i] * DDIM + t];
    }
    float sq = s * s;
    #pragma unroll
    for (int off = 1; off < 64; off <<= 1) sq += __shfl_xor(sq, off, 64);
    __shared__ float wred[2];
    if ((t & 63) == 0) wred[t >> 6] = sq;
    __syncthreads();
    const float tot = wred[0] + wred[1];
    float q = s / sqrtf(tot) + bias[t];
    q = fmaxf(q, 0.f);
    qf[row * DDIM + t] = q;
    qs[t] = q * LOG2E; // exp2-domain prescale for k_lse
    __syncthreads();
    if (t < 32) { // pack 4 dims/thread into fp8 e4m3
        int p = __builtin_amdgcn_cvt_pk_fp8_f32(qs[4 * t], qs[4 * t + 1], 0, false);
        p = __builtin_amdgcn_cvt_pk_fp8_f32(qs[4 * t + 2], qs[4 * t + 3], p, true);
        ((int*)q8)[row * 32 + t] = p;
    }
}

// ---------------- K2: MFMA logits + per-block partial sum-of-exp ------------
// FINAL anchor (82.2us, R14): R11 ordering (convwrite_reload -> raw lgkm
// barrier -> MFMA -> consume; fused in-place wr reload rides across the
// barrier) + fp8 e4m3 staging (2x8KB XOR-swizzled LDS, ds_read_b64 frags,
// cvt_pk_fp8 repack) + bias folded into MFMA C-init + exp2-domain consume.
// Session ledger: all 9 structural/occupancy deviations from this skeleton
// regressed; all retained wins were instruction deletions on it.
__global__ __launch_bounds__(256, 2)
void k_lse(const float* __restrict__ W, const float* __restrict__ b_out,
           const unsigned char* __restrict__ q8, float* __restrict__ partials) {
    __shared__ unsigned char lds[2][64 * DDIM]; // 2 x 8 KB fp8
    const int tid = threadIdx.x;
    const int lane = tid & 63;
    const int w = tid >> 6;
    const int l15 = lane & 15;
    const int l4 = lane >> 4;

    // A fragments: this wave's 64 batch rows, fp8 (8 bytes = i64 per frag)
    long a[4][4];
    #pragma unroll
    for (int mt = 0; mt < 4; ++mt)
        #pragma unroll
        for (int ks = 0; ks < 4; ++ks)
            a[mt][ks] = *(const long*)(q8 + (w * 64 + mt * 16 + l15) * DDIM + ks * 32 + 8 * l4);

    float rs[4][4];
    #pragma unroll
    for (int mt = 0; mt < 4; ++mt)
        #pragma unroll
        for (int r = 0; r < 4; ++r) rs[mt][r] = 0.f;

    // staging geometry: thread covers f32 elems (row = j*8 + tid>>5,
    // cols [(tid&31)*4, +4)); global access per j = contiguous 1KB/wave.
    const int srow = tid >> 5;
    const int scol4 = (tid & 31);       // 4-byte fp8 group index 0..31
    const int c8 = scol4 >> 1;          // dest 8B granule within row
    const int half = (scol4 & 1) * 4;   // byte offset within granule

    f32x4 wr[8];
    float bo_n[4];

    auto issue = [&](int ch) {
        const int cb = ch * 64;
        #pragma unroll
        for (int j = 0; j < 8; ++j) {
            int r = cb + j * 8 + srow;
            r = (r < OUT_DIMX) ? r : 0; // clamp: unconditional, in-bounds
            wr[j] = *(const f32x4*)(W + (size_t)r * DDIM + scol4 * 4);
        }
        #pragma unroll
        for (int nt = 0; nt < 4; ++nt) {
            int cc = cb + nt * 16 + l15;
            cc = (cc < OUT_DIMX) ? cc : 0;
            bo_n[nt] = b_out[cc] * LOG2E; // exp2-domain
        }
    };

    // Fused: per j, pack wr[j] -> 4 fp8 bytes, ds_write_b32, then immediately
    // reload wr[j] with the next chunk's row j (loads ride across the barrier).
    auto convwrite_reload = [&](int cur, bool has_next, int nch) {
        const int cb = nch * 64;
        #pragma unroll
        for (int j = 0; j < 8; ++j) {
            const int row = j * 8 + srow;
            const int sw = (c8 ^ (row & 7)) * 8 + half;
            int p = __builtin_amdgcn_cvt_pk_fp8_f32(wr[j][0], wr[j][1], 0, false);
            p = __builtin_amdgcn_cvt_pk_fp8_f32(wr[j][2], wr[j][3], p, true);
            *(int*)(&lds[cur][row * DDIM + sw]) = p;
            if (has_next) {
                int r = cb + j * 8 + srow;
                r = (r < OUT_DIMX) ? r : 0;
                wr[j] = *(const f32x4*)(W + (size_t)r * DDIM + scol4 * 4);
            }
        }
    };

    int cur = 0;
    issue(blockIdx.x);
    for (int ch = blockIdx.x; ch < NCHUNK; ch += NBLK) {
        float bo_c[4];
        #pragma unroll
        for (int nt = 0; nt < 4; ++nt) bo_c[nt] = bo_n[nt];

        const bool has_next = (ch + NBLK < NCHUNK);
        convwrite_reload(cur, has_next, has_next ? ch + NBLK : 0);
        if (has_next) { // next chunk's b_out rides with the W loads
            const int cb = (ch + NBLK) * 64;
            #pragma unroll
            for (int nt = 0; nt < 4; ++nt) {
                int cc = cb + nt * 16 + l15;
                cc = (cc < OUT_DIMX) ? cc : 0;
                bo_n[nt] = b_out[cc] * LOG2E;
            }
        }
        // RAW barrier: wait only LDS writes; W loads stay in flight across it.
        asm volatile("s_waitcnt lgkmcnt(0)" ::: "memory");
        __builtin_amdgcn_s_barrier();
        asm volatile("" ::: "memory"); // no ds_read hoist above barrier

        f32x4 acc[4][4]; // C-init = per-class bias (exp2-domain)
        #pragma unroll
        for (int mt = 0; mt < 4; ++mt)
            #pragma unroll
            for (int nt = 0; nt < 4; ++nt)
                acc[mt][nt] = (f32x4){bo_c[nt], bo_c[nt], bo_c[nt], bo_c[nt]};

        #pragma unroll
        for (int ks = 0; ks < 4; ++ks) {
            #pragma unroll
            for (int nt = 0; nt < 4; ++nt) {
                const int row = nt * 16 + l15;
                const int g = (ks * 4 + l4) ^ (row & 7);
                const long b = *(const long*)(&lds[cur][row * DDIM + g * 8]);
                #pragma unroll
                for (int mt = 0; mt < 4; ++mt)
                    acc[mt][nt] = __builtin_amdgcn_mfma_f32_16x16x32_fp8_fp8(
                        a[mt][ks], b, acc[mt][nt], 0, 0, 0);
            }
        }

        // consume: rs += exp2(acc)  (bias already in acc; exp2-domain)
        const int cbase = ch * 64;
        if (cbase + 64 <= OUT_DIMX) { // full chunk: no masking
            #pragma unroll
            for (int nt = 0; nt < 4; ++nt)
                #pragma unroll
                for (int mt = 0; mt < 4; ++mt)
                    #pragma unroll
                    for (int r = 0; r < 4; ++r)
                        rs[mt][r] += __builtin_amdgcn_exp2f(acc[mt][nt][r]);
        } else { // single partial tail chunk
            #pragma unroll
            for (int nt = 0; nt < 4; ++nt) {
                const bool valid = (cbase + nt * 16 + l15 < OUT_DIMX);
                #pragma unroll
                for (int mt = 0; mt < 4; ++mt)
                    #pragma unroll
                    for (int r = 0; r < 4; ++r)
                        rs[mt][r] += valid ? __builtin_amdgcn_exp2f(acc[mt][nt][r]) : 0.f;
            }
        }
        cur ^= 1;
    }

    // reduce across the 16 lanes sharing each batch row; transposed layout
    // partials[row * NBLK + blk] so k_rowlse reads coalesced.
    #pragma unroll
    for (int mt = 0; mt < 4; ++mt)
        #pragma unroll
        for (int r = 0; r < 4; ++r) {
            float v = rs[mt][r];
            v += __shfl_xor(v, 1, 64);
            v += __shfl_xor(v, 2, 64);
            v += __shfl_xor(v, 4, 64);
            v += __shfl_xor(v, 8, 64);
            if (l15 == 0) {
                const int rowb = w * 64 + mt * 16 + l4 * 4 + r;
                partials[(size_t)rowb * NBLK + blockIdx.x] = v;
            }
        }
}

// ---------------- K3: per-row logsumexp + label logit -> per-row loss -------
// partials hold sums of 2^(l*log2e) = e^l, so LSE_natural = logf(s).
__global__ void k_rowlse(const float* __restrict__ partials,
                         const int* __restrict__ y,
                         const float* __restrict__ qf,
                         const float* __restrict__ W,
                         const float* __restrict__ b_out,
                         float* __restrict__ rowloss) {
    const int i = blockIdx.x;     // batch row
    const int lane = threadIdx.x; // 64
    float s = 0.f;
    #pragma unroll
    for (int k = 0; k < NBLK / 64; ++k)
        s += partials[(size_t)i * NBLK + k * 64 + lane];
    // label logit: dot(q_i, W[y_i]) fused here (exact f32)
    const int yi = y[i];
    const float* wrow = W + (size_t)yi * DDIM;
    const float* qrow = qf + i * DDIM;
    float d = qrow[lane] * wrow[lane] + qrow[lane + 64] * wrow[lane + 64];
    #pragma unroll
    for (int off = 1; off < 64; off <<= 1) {
        s += __shfl_xor(s, off, 64);
        d += __shfl_xor(d, off, 64);
    }
    if (lane == 0) rowloss[i] = logf(s) - (d + b_out[yi]);
}

// ---------------- K4: mean over batch -> scalar loss ------------------------
__global__ void k_final(const float* __restrict__ rowloss, float* __restrict__ out) {
    const int i = threadIdx.x; // 256
    float t = rowloss[i];
    #pragma unroll
    for (int off = 1; off < 64; off <<= 1) t += __shfl_xor(t, off, 64);
    __shared__ float wred[4];
    if ((threadIdx.x & 63) == 0) wred[threadIdx.x >> 6] = t;
    __syncthreads();
    if (threadIdx.x == 0)
        out[0] = (wred[0] + wred[1] + wred[2] + wred[3]) * (1.0f / (float)BATCH);
}

extern "C" void kernel_launch(void* const* d_in, const int* in_sizes, int n_in,
                              void* d_out, int out_size, void* d_ws, size_t ws_size,
                              hipStream_t stream) {
    const int*   x     = (const int*)d_in[0];
    const int*   y     = (const int*)d_in[1];
    // d_in[2] = freeze, d_in[3] = slide (unused: exact/full softmax path)
    const float* emb   = (const float*)d_in[4];
    const float* bias  = (const float*)d_in[5];
    const float* W     = (const float*)d_in[6];
    const float* b_out = (const float*)d_in[7];
    float* out = (float*)d_out;

    char* ws = (char*)d_ws;
    unsigned char* q8 = (unsigned char*)(ws);   // 256*128 = 32 KB fp8 (q*log2e)
    float*  qf       = (float*)(ws + 65536);    // 256*128*4 = 128 KB (exact)
    float*  rowloss  = (float*)(ws + 197632);   // 1 KB
    float*  partials = (float*)(ws + 262144);   // 256*NBLK*4 = 512 KB

    k_query<<<BATCH, DDIM, 0, stream>>>(x, emb, bias, qf, q8);
    k_lse<<<NBLK, 256, 0, stream>>>(W, b_out, q8, partials);
    k_rowlse<<<BATCH, 64, 0, stream>>>(partials, y, qf, W, b_out, rowloss);
    k_final<<<1, 256, 0, stream>>>(rowloss, out);
}